// Round 1
// baseline (532.843 us; speedup 1.0000x reference)
//
#include <hip/hip_runtime.h>
#include <math.h>

// SPOPFNS attention, MI355X fp32 baseline.
// B=2 H=8 N=2048 D=64; alpha=1, d_int=4 -> exponent -5; bw=1; a=0.5; R=1.
#define B_ 2
#define H_ 8
#define N_ 2048
#define D_ 64
#define BH_ (B_*H_)
#define TILE 64
#define LSTR 68   // LDS row stride in floats (68*4B = 272B = 16B-aligned rows)

// Cephes asinf core polynomial: asin(x) = x + x*z*P(z), z=x^2, |x|<=0.5
__device__ __forceinline__ float acos_poly(float z){
  float p = 4.2163199048e-2f;
  p = __builtin_fmaf(p, z, 2.4181311049e-2f);
  p = __builtin_fmaf(p, z, 4.5470025998e-2f);
  p = __builtin_fmaf(p, z, 7.4953002686e-2f);
  p = __builtin_fmaf(p, z, 1.6666752422e-1f);
  return p;
}

// score = (1 + geodesic)^(-5); masked keys get geodesic = 10000.
__device__ __forceinline__ float score_fn(float qk, float masked){
  const float LO = -1.0f + 1e-7f;
  const float HI =  1.0f - 1e-7f;
  float x  = fminf(fmaxf(qk, LO), HI);
  float ax = fabsf(x);
  bool big = ax > 0.5f;
  float z  = big ? (0.5f*(1.0f - ax)) : (x*x);
  float s  = big ? __builtin_amdgcn_sqrtf(z) : x;   // sign kept in small branch
  float p  = acos_poly(z);
  float r  = __builtin_fmaf(s*z, p, s);             // asin(s) (or asin(x))
  float g_big   = (x >= 0.0f) ? (2.0f*r) : __builtin_fmaf(-2.0f, r, 3.14159265358979f);
  float g_small = 1.57079632679490f - r;
  float g = big ? g_big : g_small;
  g = (masked != 0.0f) ? 10000.0f : g;
  float w1 = 1.0f + g;
  float w2 = w1*w1;
  float w4 = w2*w2;
  float w5 = w4*w1;
  return __builtin_amdgcn_rcpf(w5);                 // (1+g)^-5
}

// ---------------- Pass 1: column degrees -> w[m] = n_c^-0.5 ----------------
__global__ __launch_bounds__(256) void spop_pass1(
    const float* __restrict__ Q, const float* __restrict__ K,
    const int* __restrict__ mask, float* __restrict__ w)
{
  __shared__ float Ks[TILE*LSTR];   // [k][key]  transposed
  __shared__ float Qs[TILE*LSTR];   // [k][row]  transposed
  __shared__ float msk[TILE];
  __shared__ float red[TILE*17];

  const int kt  = blockIdx.x;       // key tile 0..31
  const int bh  = blockIdx.y;       // 0..15
  const int b   = bh >> 3;
  const int tid = threadIdx.x;
  const int tx  = tid & 15;
  const int ty  = tid >> 4;

  const float* Qg = Q + (size_t)bh * N_ * D_;
  const float* Kg = K + (size_t)bh * N_ * D_ + (size_t)kt * TILE * D_;

  #pragma unroll
  for (int it = 0; it < 4; ++it){
    int idx = tid + it*256;
    int r   = idx >> 4;
    int c4  = (idx & 15) << 2;
    const float4 v = *(const float4*)(Kg + r*D_ + c4);
    Ks[(c4+0)*LSTR + r] = v.x;
    Ks[(c4+1)*LSTR + r] = v.y;
    Ks[(c4+2)*LSTR + r] = v.z;
    Ks[(c4+3)*LSTR + r] = v.w;
  }
  if (tid < TILE)
    msk[tid] = (mask[b*N_ + kt*TILE + tid] == 0) ? 1.0f : 0.0f;

  float cs[4] = {0.f,0.f,0.f,0.f};

  for (int rt = 0; rt < N_/TILE; ++rt){
    __syncthreads();
    #pragma unroll
    for (int it = 0; it < 4; ++it){
      int idx = tid + it*256;
      int r   = idx >> 4;
      int c4  = (idx & 15) << 2;
      const float4 v = *(const float4*)(Qg + (size_t)(rt*TILE + r)*D_ + c4);
      Qs[(c4+0)*LSTR + r] = v.x;
      Qs[(c4+1)*LSTR + r] = v.y;
      Qs[(c4+2)*LSTR + r] = v.z;
      Qs[(c4+3)*LSTR + r] = v.w;
    }
    __syncthreads();

    float acc[4][4] = {};
    #pragma unroll
    for (int k = 0; k < TILE; ++k){
      float4 qv = *(const float4*)&Qs[k*LSTR + 4*ty];
      float4 kv = *(const float4*)&Ks[k*LSTR + 4*tx];
      float qa[4] = {qv.x, qv.y, qv.z, qv.w};
      float ka[4] = {kv.x, kv.y, kv.z, kv.w};
      #pragma unroll
      for (int i = 0; i < 4; ++i)
        #pragma unroll
        for (int j = 0; j < 4; ++j)
          acc[i][j] = __builtin_fmaf(qa[i], ka[j], acc[i][j]);
    }
    float mj[4];
    #pragma unroll
    for (int j = 0; j < 4; ++j) mj[j] = msk[4*tx + j];
    #pragma unroll
    for (int i = 0; i < 4; ++i)
      #pragma unroll
      for (int j = 0; j < 4; ++j)
        cs[j] += score_fn(acc[i][j], mj[j]);
  }

  __syncthreads();
  #pragma unroll
  for (int j = 0; j < 4; ++j) red[(4*tx + j)*17 + ty] = cs[j];
  __syncthreads();
  if (tid < TILE){
    float s = 0.f;
    #pragma unroll
    for (int t = 0; t < 16; ++t) s += red[tid*17 + t];
    w[bh*N_ + kt*TILE + tid] = 1.0f / sqrtf(s);   // n_c^-0.5
  }
}

// ---------------- Pass 2: out[n,:] = sum_m S*w[m]*V[m,:] / sum_m S*w[m] ----
__global__ __launch_bounds__(256) void spop_pass2(
    const float* __restrict__ Q, const float* __restrict__ K,
    const float* __restrict__ V, const int* __restrict__ mask,
    const float* __restrict__ w, float* __restrict__ out)
{
  __shared__ float Qs[TILE*LSTR];   // [k][row]   transposed, persistent
  __shared__ float Ks[TILE*LSTR];   // [k][key]   transposed
  __shared__ float Vs[TILE*LSTR];   // [key][d]   natural
  __shared__ float Ss[TILE*LSTR];   // [key][row] transposed scores
  __shared__ float msk[TILE];
  __shared__ float wms[TILE];
  __shared__ float red[TILE*17];
  __shared__ float rsum[TILE];

  const int rt  = blockIdx.x;       // row tile 0..31
  const int bh  = blockIdx.y;
  const int b   = bh >> 3;
  const int tid = threadIdx.x;
  const int tx  = tid & 15;
  const int ty  = tid >> 4;

  const float* Qg = Q + (size_t)bh*N_*D_ + (size_t)rt*TILE*D_;
  const float* Kg = K + (size_t)bh*N_*D_;
  const float* Vg = V + (size_t)bh*N_*D_;

  #pragma unroll
  for (int it = 0; it < 4; ++it){
    int idx = tid + it*256;
    int r   = idx >> 4;
    int c4  = (idx & 15) << 2;
    const float4 v = *(const float4*)(Qg + r*D_ + c4);
    Qs[(c4+0)*LSTR + r] = v.x;
    Qs[(c4+1)*LSTR + r] = v.y;
    Qs[(c4+2)*LSTR + r] = v.z;
    Qs[(c4+3)*LSTR + r] = v.w;
  }

  float acc[4][4] = {};
  float rs[4] = {0.f,0.f,0.f,0.f};

  for (int kt = 0; kt < N_/TILE; ++kt){
    __syncthreads();   // protects Ks/Vs/Ss from previous iteration
    #pragma unroll
    for (int it = 0; it < 4; ++it){
      int idx = tid + it*256;
      int r   = idx >> 4;
      int c4  = (idx & 15) << 2;
      const float4 kv = *(const float4*)(Kg + (size_t)(kt*TILE + r)*D_ + c4);
      Ks[(c4+0)*LSTR + r] = kv.x;
      Ks[(c4+1)*LSTR + r] = kv.y;
      Ks[(c4+2)*LSTR + r] = kv.z;
      Ks[(c4+3)*LSTR + r] = kv.w;
      const float4 vv = *(const float4*)(Vg + (size_t)(kt*TILE + r)*D_ + c4);
      *(float4*)&Vs[r*LSTR + c4] = vv;
    }
    if (tid < TILE){
      int gk = kt*TILE + tid;
      msk[tid] = (mask[b*N_ + gk] == 0) ? 1.0f : 0.0f;
      wms[tid] = w[bh*N_ + gk];
    }
    __syncthreads();

    float s[4][4] = {};
    #pragma unroll
    for (int k = 0; k < TILE; ++k){
      float4 qv = *(const float4*)&Qs[k*LSTR + 4*ty];
      float4 kv = *(const float4*)&Ks[k*LSTR + 4*tx];
      float qa[4] = {qv.x, qv.y, qv.z, qv.w};
      float ka[4] = {kv.x, kv.y, kv.z, kv.w};
      #pragma unroll
      for (int i = 0; i < 4; ++i)
        #pragma unroll
        for (int j = 0; j < 4; ++j)
          s[i][j] = __builtin_fmaf(qa[i], ka[j], s[i][j]);
    }

    float mj[4], wj[4];
    #pragma unroll
    for (int j = 0; j < 4; ++j){ mj[j] = msk[4*tx+j]; wj[j] = wms[4*tx+j]; }
    #pragma unroll
    for (int i = 0; i < 4; ++i){
      #pragma unroll
      for (int j = 0; j < 4; ++j){
        float sc = score_fn(s[i][j], mj[j]) * wj[j];
        rs[i] += sc;
        Ss[(4*tx+j)*LSTR + (4*ty+i)] = sc;   // transposed [key][row]
      }
    }
    __syncthreads();   // Ss ready

    #pragma unroll
    for (int m = 0; m < TILE; ++m){
      float4 sv = *(const float4*)&Ss[m*LSTR + 4*ty];
      float4 vv = *(const float4*)&Vs[m*LSTR + 4*tx];
      float sa[4] = {sv.x, sv.y, sv.z, sv.w};
      float va[4] = {vv.x, vv.y, vv.z, vv.w};
      #pragma unroll
      for (int i = 0; i < 4; ++i)
        #pragma unroll
        for (int j = 0; j < 4; ++j)
          acc[i][j] = __builtin_fmaf(sa[i], va[j], acc[i][j]);
    }
  }

  __syncthreads();
  #pragma unroll
  for (int i = 0; i < 4; ++i) red[(4*ty+i)*17 + tx] = rs[i];
  __syncthreads();
  if (tid < TILE){
    float ssum = 0.f;
    #pragma unroll
    for (int t = 0; t < 16; ++t) ssum += red[tid*17 + t];
    rsum[tid] = 1.0f / fmaxf(ssum, 1e-12f);
  }
  __syncthreads();

  float* Og = out + (size_t)bh*N_*D_ + (size_t)rt*TILE*D_;
  #pragma unroll
  for (int i = 0; i < 4; ++i){
    float inv = rsum[4*ty+i];
    float4 o;
    o.x = acc[i][0]*inv;
    o.y = acc[i][1]*inv;
    o.z = acc[i][2]*inv;
    o.w = acc[i][3]*inv;
    *(float4*)(Og + (size_t)(4*ty+i)*D_ + 4*tx) = o;
  }
}

extern "C" void kernel_launch(void* const* d_in, const int* in_sizes, int n_in,
                              void* d_out, int out_size, void* d_ws, size_t ws_size,
                              hipStream_t stream) {
  (void)in_sizes; (void)n_in; (void)out_size; (void)ws_size;
  const float* Q   = (const float*)d_in[0];
  const float* K   = (const float*)d_in[1];
  const float* V   = (const float*)d_in[2];
  const int*  mask = (const int*)d_in[3];
  float* out = (float*)d_out;
  float* w   = (float*)d_ws;   // BH_*N_ floats = 128 KB

  dim3 grid(N_/TILE, BH_);
  spop_pass1<<<grid, 256, 0, stream>>>(Q, K, mask, w);
  spop_pass2<<<grid, 256, 0, stream>>>(Q, K, V, mask, w, out);
}

// Round 3
// 326.660 us; speedup vs baseline: 1.6312x; 1.6312x over previous
//
#include <hip/hip_runtime.h>
#include <hip/hip_bf16.h>
#include <math.h>

// SPOPFNS attention, MI355X — MFMA (bf16 split) version.
// B=2 H=8 N=2048 D=64; exponent -5; a=0.5. Two passes:
//   pass1: column degrees n_c -> w[m] = n_c^-0.5   (row factor cancels in p=1 norm)
//   pass2: out = (S*w) V / rowsum(S*w), flash-style over key tiles.
// Both compute S^T tiles D[key][row] = K·Q^T with mfma_f32_16x16x32_bf16.
#define B_ 2
#define H_ 8
#define N_ 2048
#define D_ 64
#define BH_ 16
#define NT_ (N_/64)
#define LS 72          // LDS row stride in ushorts (144B, 16B-aligned rows)
#define LSW (LS/2)     // same in dwords

typedef __attribute__((ext_vector_type(8))) short short8;
typedef __attribute__((ext_vector_type(4))) float float4v;

__device__ __forceinline__ unsigned packbf2(float a, float b){
  __hip_bfloat162 h = __float22bfloat162_rn(make_float2(a, b));
  return *(unsigned*)&h;
}
// hi = packed bf16(a,b); lo = packed bf16 of residuals
__device__ __forceinline__ void split2(float a, float b, unsigned& hi, unsigned& lo){
  hi = packbf2(a, b);
  float ha = __uint_as_float(hi << 16);
  float hb = __uint_as_float(hi & 0xFFFF0000u);
  lo = packbf2(a - ha, b - hb);
}
// load 8 consecutive floats, split into bf16 hi/lo MFMA fragments
__device__ __forceinline__ void load_split8(const float* p, short8& hi8, short8& lo8){
  float4v v0 = *(const float4v*)p;
  float4v v1 = *(const float4v*)(p + 4);
  unsigned h0,h1,h2,h3,l0,l1,l2,l3;
  split2(v0.x, v0.y, h0, l0);
  split2(v0.z, v0.w, h1, l1);
  split2(v1.x, v1.y, h2, l2);
  split2(v1.z, v1.w, h3, l3);
  unsigned ph[4] = {h0,h1,h2,h3};
  unsigned pl[4] = {l0,l1,l2,l3};
  hi8 = *(short8*)ph;
  lo8 = *(short8*)pl;
}

__device__ __forceinline__ float acos_poly(float z){
  float p = 4.2163199048e-2f;
  p = __builtin_fmaf(p, z, 2.4181311049e-2f);
  p = __builtin_fmaf(p, z, 4.5470025998e-2f);
  p = __builtin_fmaf(p, z, 7.4953002686e-2f);
  p = __builtin_fmaf(p, z, 1.6666752422e-1f);
  return p;
}
// score = (1 + acos(clip(qk)))^(-5); masked keys get g = 10000.
__device__ __forceinline__ float score_fn(float qk, float masked){
  const float LO = -1.0f + 1e-7f;
  const float HI =  1.0f - 1e-7f;
  float x  = fminf(fmaxf(qk, LO), HI);
  float ax = fabsf(x);
  bool big = ax > 0.5f;
  float z  = big ? (0.5f*(1.0f - ax)) : (x*x);
  float s  = big ? __builtin_amdgcn_sqrtf(z) : x;
  float p  = acos_poly(z);
  float r  = __builtin_fmaf(s*z, p, s);
  float g_big   = (x >= 0.0f) ? (2.0f*r) : __builtin_fmaf(-2.0f, r, 3.14159265358979f);
  float g_small = 1.57079632679490f - r;
  float g = big ? g_big : g_small;
  g = (masked != 0.0f) ? 10000.0f : g;
  float w1 = 1.0f + g;
  float w2 = w1*w1;
  float w4 = w2*w2;
  float w5 = w4*w1;
  return __builtin_amdgcn_rcpf(w5);
}

// ---------------- Pass 1: column degrees -> w[m] = n_c^-0.5 ----------------
__global__ __launch_bounds__(256) void spop_pass1(
    const float* __restrict__ Q, const float* __restrict__ K,
    const int* __restrict__ mask, float* __restrict__ wout)
{
  __shared__ unsigned short Qhi[64*LS], Qlo[64*LS];
  __shared__ float msk[64];
  __shared__ float red[64*4];

  const int kt = blockIdx.x, bh = blockIdx.y, b = bh>>3;
  const int tid = threadIdx.x;
  const int wv = tid>>6, lane = tid&63, quad = lane>>4, l15 = lane&15;

  const float* Qg = Q + (size_t)bh*N_*D_;
  const float* Kg = K + (size_t)bh*N_*D_;

  // block-resident K fragments (A operand, m=key): 4 key subtiles x 2 k-chunks
  short8 khi[4][2], klo[4][2];
  #pragma unroll
  for (int s=0;s<4;++s){
    const float* kp = Kg + (size_t)(kt*64 + s*16 + l15)*D_ + quad*8;
    load_split8(kp,      khi[s][0], klo[s][0]);
    load_split8(kp + 32, khi[s][1], klo[s][1]);
  }
  if (tid < 64)
    msk[tid] = (mask[b*N_ + kt*64 + tid] == 0) ? 1.f : 0.f;

  float cs[4][4];
  #pragma unroll
  for (int s=0;s<4;++s)
    #pragma unroll
    for (int i=0;i<4;++i) cs[s][i] = 0.f;

  for (int rt=0; rt<NT_; ++rt){
    __syncthreads();
    #pragma unroll
    for (int it=0; it<4; ++it){
      int idx = tid + it*256;
      int r = idx>>4, d4 = (idx&15)<<2;
      const float4v v = *(const float4v*)(Qg + (size_t)(rt*64 + r)*D_ + d4);
      unsigned h0,l0,h1,l1;
      split2(v.x, v.y, h0, l0);
      split2(v.z, v.w, h1, l1);
      unsigned* QhiW = (unsigned*)Qhi; unsigned* QloW = (unsigned*)Qlo;
      int base = r*LSW + (d4>>1);
      QhiW[base] = h0; QhiW[base+1] = h1;
      QloW[base] = l0; QloW[base+1] = l1;
    }
    __syncthreads();

    short8 bhi[2], blo[2];
    #pragma unroll
    for (int cc=0; cc<2; ++cc){
      bhi[cc] = *(const short8*)&Qhi[(wv*16+l15)*LS + cc*32 + quad*8];
      blo[cc] = *(const short8*)&Qlo[(wv*16+l15)*LS + cc*32 + quad*8];
    }
    #pragma unroll
    for (int s=0;s<4;++s){
      float4v c = {0.f,0.f,0.f,0.f};
      #pragma unroll
      for (int cc=0; cc<2; ++cc){
        c = __builtin_amdgcn_mfma_f32_16x16x32_bf16(khi[s][cc], bhi[cc], c, 0,0,0);
        c = __builtin_amdgcn_mfma_f32_16x16x32_bf16(khi[s][cc], blo[cc], c, 0,0,0);
        c = __builtin_amdgcn_mfma_f32_16x16x32_bf16(klo[s][cc], bhi[cc], c, 0,0,0);
      }
      int kl = s*16 + quad*4;
      #pragma unroll
      for (int i=0;i<4;++i)
        cs[s][i] += score_fn(c[i], msk[kl+i]);
    }
  }

  // sum over the 16 query-rows held across l15 lanes (per wave)
  #pragma unroll
  for (int s=0;s<4;++s)
    #pragma unroll
    for (int i=0;i<4;++i){
      float v2 = cs[s][i];
      v2 += __shfl_xor(v2, 1);
      v2 += __shfl_xor(v2, 2);
      v2 += __shfl_xor(v2, 4);
      v2 += __shfl_xor(v2, 8);
      cs[s][i] = v2;
    }
  if (l15 == 0){
    #pragma unroll
    for (int s=0;s<4;++s)
      #pragma unroll
      for (int i=0;i<4;++i)
        red[(s*16 + quad*4 + i)*4 + wv] = cs[s][i];
  }
  __syncthreads();
  if (tid < 64){
    float t = red[tid*4+0] + red[tid*4+1] + red[tid*4+2] + red[tid*4+3];
    wout[bh*N_ + kt*64 + tid] = 1.0f / sqrtf(t);
  }
}

// ---------------- Pass 2: out[n,:] = sum_m S*w[m]*V[m,:] / sum_m S*w[m] ----
__global__ __launch_bounds__(256) void spop_pass2(
    const float* __restrict__ Q, const float* __restrict__ K,
    const float* __restrict__ V, const int* __restrict__ mask,
    const float* __restrict__ w, float* __restrict__ out)
{
  __shared__ unsigned short Khi[64*LS], Klo[64*LS];
  __shared__ unsigned short Vt[64*LS];    // [d][key] transposed, bf16
  __shared__ unsigned short Ps[64*LS];    // [row][key] bf16 scores (per-wave rows)
  __shared__ float msk[64], wms[64];

  const int rt = blockIdx.x, bh = blockIdx.y, b = bh>>3;
  const int tid = threadIdx.x;
  const int wv = tid>>6, lane = tid&63, quad = lane>>4, l15 = lane&15;

  const float* Qg = Q + (size_t)bh*N_*D_;
  const float* Kg = K + (size_t)bh*N_*D_;
  const float* Vg = V + (size_t)bh*N_*D_;

  // loop-invariant Q fragments (B operand, n=row): this wave's 16 rows
  short8 qhi[2], qlo[2];
  {
    const float* qp = Qg + (size_t)(rt*64 + wv*16 + l15)*D_ + quad*8;
    load_split8(qp,      qhi[0], qlo[0]);
    load_split8(qp + 32, qhi[1], qlo[1]);
  }

  float4v acc[4];
  #pragma unroll
  for (int i=0;i<4;++i) acc[i] = (float4v){0.f,0.f,0.f,0.f};
  float rs = 0.f;

  for (int kt=0; kt<NT_; ++kt){
    __syncthreads();
    // stage K hi/lo [key][d]
    #pragma unroll
    for (int it=0; it<4; ++it){
      int idx = tid + it*256;
      int r = idx>>4, d4 = (idx&15)<<2;
      const float4v v = *(const float4v*)(Kg + (size_t)(kt*64 + r)*D_ + d4);
      unsigned h0,l0,h1,l1;
      split2(v.x, v.y, h0, l0);
      split2(v.z, v.w, h1, l1);
      unsigned* KhiW = (unsigned*)Khi; unsigned* KloW = (unsigned*)Klo;
      int base = r*LSW + (d4>>1);
      KhiW[base] = h0; KhiW[base+1] = h1;
      KloW[base] = l0; KloW[base+1] = l1;
    }
    // stage V transposed [d][key], bf16 (pairs of keys -> packed dwords)
    #pragma unroll
    for (int it=0; it<2; ++it){
      int u = tid + it*256;
      int kp = u & 31;            // key pair index
      int d4 = (u>>5)<<2;         // 0..60
      const float* vp = Vg + (size_t)(kt*64 + kp*2)*D_ + d4;
      float4v a0 = *(const float4v*)vp;
      float4v a1 = *(const float4v*)(vp + D_);
      unsigned* VtW = (unsigned*)Vt;
      VtW[(d4+0)*LSW + kp] = packbf2(a0.x, a1.x);
      VtW[(d4+1)*LSW + kp] = packbf2(a0.y, a1.y);
      VtW[(d4+2)*LSW + kp] = packbf2(a0.z, a1.z);
      VtW[(d4+3)*LSW + kp] = packbf2(a0.w, a1.w);
    }
    if (tid < 64){
      int gk = kt*64 + tid;
      msk[tid] = (mask[b*N_ + gk] == 0) ? 1.f : 0.f;
      wms[tid] = w[bh*N_ + gk];
    }
    __syncthreads();

    // S^T tiles: D[key][row], transform, write P to LDS (own rows only)
    #pragma unroll
    for (int s=0;s<4;++s){
      float4v c = {0.f,0.f,0.f,0.f};
      #pragma unroll
      for (int cc=0; cc<2; ++cc){
        const short8 ahi = *(const short8*)&Khi[(s*16+l15)*LS + cc*32 + quad*8];
        const short8 alo = *(const short8*)&Klo[(s*16+l15)*LS + cc*32 + quad*8];
        c = __builtin_amdgcn_mfma_f32_16x16x32_bf16(ahi, qhi[cc], c, 0,0,0);
        c = __builtin_amdgcn_mfma_f32_16x16x32_bf16(ahi, qlo[cc], c, 0,0,0);
        c = __builtin_amdgcn_mfma_f32_16x16x32_bf16(alo, qhi[cc], c, 0,0,0);
      }
      int kl = s*16 + quad*4;
      float sc0 = score_fn(c[0], msk[kl+0]) * wms[kl+0];
      float sc1 = score_fn(c[1], msk[kl+1]) * wms[kl+1];
      float sc2 = score_fn(c[2], msk[kl+2]) * wms[kl+2];
      float sc3 = score_fn(c[3], msk[kl+3]) * wms[kl+3];
      rs += (sc0 + sc1) + (sc2 + sc3);
      unsigned* PsW = (unsigned*)Ps;
      int pb = (wv*16 + l15)*LSW + (kl>>1);
      PsW[pb]   = packbf2(sc0, sc1);
      PsW[pb+1] = packbf2(sc2, sc3);
    }

    // P·V transposed: D[d][row] accumulate (within-wave LDS dependency on Ps)
    short8 pf[2];
    pf[0] = *(const short8*)&Ps[(wv*16+l15)*LS +  0 + quad*8];
    pf[1] = *(const short8*)&Ps[(wv*16+l15)*LS + 32 + quad*8];
    #pragma unroll
    for (int s2=0;s2<4;++s2){
      #pragma unroll
      for (int cc=0; cc<2; ++cc){
        const short8 av = *(const short8*)&Vt[(s2*16+l15)*LS + cc*32 + quad*8];
        acc[s2] = __builtin_amdgcn_mfma_f32_16x16x32_bf16(av, pf[cc], acc[s2], 0,0,0);
      }
    }
  }

  // full rowsum for row = wv*16 + l15 (combine the 4 quads' key partials)
  rs += __shfl_xor(rs, 16);
  rs += __shfl_xor(rs, 32);
  float inv = 1.0f / fmaxf(rs, 1e-12f);

  float* Og = out + (size_t)bh*N_*D_ + (size_t)(rt*64 + wv*16 + l15)*D_;
  #pragma unroll
  for (int s2=0;s2<4;++s2)
    #pragma unroll
    for (int i=0;i<4;++i)
      Og[s2*16 + quad*4 + i] = acc[s2][i] * inv;
}

extern "C" void kernel_launch(void* const* d_in, const int* in_sizes, int n_in,
                              void* d_out, int out_size, void* d_ws, size_t ws_size,
                              hipStream_t stream) {
  (void)in_sizes; (void)n_in; (void)out_size; (void)ws_size;
  const float* Q   = (const float*)d_in[0];
  const float* K   = (const float*)d_in[1];
  const float* V   = (const float*)d_in[2];
  const int*  mask = (const int*)d_in[3];
  float* out = (float*)d_out;
  float* w   = (float*)d_ws;   // BH_*N_ floats = 128 KB

  dim3 grid(NT_, BH_);
  spop_pass1<<<grid, 256, 0, stream>>>(Q, K, mask, w);
  spop_pass2<<<grid, 256, 0, stream>>>(Q, K, V, mask, w, out);
}

// Round 6
// 234.440 us; speedup vs baseline: 2.2728x; 1.3934x over previous
//
#include <hip/hip_runtime.h>
#include <hip/hip_bf16.h>
#include <math.h>

#define B_ 2
#define H_ 8
#define N_ 2048
#define D_ 64
#define BH_ 16
#define NT_ (N_/64)
#define LS 72
#define LSW (LS/2)

typedef __attribute__((ext_vector_type(8))) short short8;
typedef __attribute__((ext_vector_type(4))) float float4v;

__device__ __forceinline__ unsigned packbf2(float a, float b){
  __hip_bfloat162 h = __float22bfloat162_rn(make_float2(a, b));
  return *(unsigned*)&h;
}
__device__ __forceinline__ void split2(float a, float b, unsigned& hi, unsigned& lo){
  hi = packbf2(a, b);
  float ha = __uint_as_float(hi << 16);
  float hb = __uint_as_float(hi & 0xFFFF0000u);
  lo = packbf2(a - ha, b - hb);
}
__device__ __forceinline__ void load_split8(const float* p, short8& hi8, short8& lo8){
  float4v v0 = *(const float4v*)p;
  float4v v1 = *(const float4v*)(p + 4);
  unsigned h0,h1,h2,h3,l0,l1,l2,l3;
  split2(v0.x, v0.y, h0, l0);
  split2(v0.z, v0.w, h1, l1);
  split2(v1.x, v1.y, h2, l2);
  split2(v1.z, v1.w, h3, l3);
  unsigned ph[4] = {h0,h1,h2,h3};
  unsigned pl[4] = {l0,l1,l2,l3};
  hi8 = *(short8*)ph;
  lo8 = *(short8*)pl;
}
__device__ __forceinline__ float acos_poly(float z){
  float p = 4.2163199048e-2f;
  p = __builtin_fmaf(p, z, 2.4181311049e-2f);
  p = __builtin_fmaf(p, z, 4.5470025998e-2f);
  p = __builtin_fmaf(p, z, 7.4953002686e-2f);
  p = __builtin_fmaf(p, z, 1.6666752422e-1f);
  return p;
}
__device__ __forceinline__ float score_fn(float qk, float masked){
  const float LO = -1.0f + 1e-7f;
  const float HI =  1.0f - 1e-7f;
  float x  = fminf(fmaxf(qk, LO), HI);
  float ax = fabsf(x);
  bool big = ax > 0.5f;
  float z  = big ? (0.5f*(1.0f - ax)) : (x*x);
  float s  = big ? __builtin_amdgcn_sqrtf(z) : x;
  float p  = acos_poly(z);
  float r  = __builtin_fmaf(s*z, p, s);
  float g_big   = (x >= 0.0f) ? (2.0f*r) : __builtin_fmaf(-2.0f, r, 3.14159265358979f);
  float g_small = 1.57079632679490f - r;
  float g = big ? g_big : g_small;
  g = (masked != 0.0f) ? 10000.0f : g;
  float w1 = 1.0f + g;
  float w2 = w1*w1;
  float w4 = w2*w2;
  float w5 = w4*w1;
  return __builtin_amdgcn_rcpf(w5);
}

// k1 (STORE=true): scores -> S bf16, col sums atomically into ncw.
// k1 (STORE=false): full column sums, ncw = n_c^-0.5 directly (fallback pass1).
template<bool STORE>
__global__ __launch_bounds__(256) void k1_score(
    const float* __restrict__ Q, const float* __restrict__ K,
    const int* __restrict__ mask, float* __restrict__ ncw,
    unsigned short* __restrict__ S)
{
  __shared__ unsigned short Qhi[64*LS], Qlo[64*LS];
  __shared__ float msk[64];
  __shared__ float red[64*4];

  const int kt = blockIdx.x, bh = blockIdx.y, rz = blockIdx.z;
  const int nz = gridDim.z;
  const int tid = threadIdx.x;
  const int wv = tid>>6, lane = tid&63, quad = lane>>4, l15 = lane&15;

  const float* Qg = Q + (size_t)bh*N_*D_;
  const float* Kg = K + (size_t)bh*N_*D_;

  short8 khi[4][2], klo[4][2];
  #pragma unroll
  for (int s=0;s<4;++s){
    const float* kp = Kg + (size_t)(kt*64 + s*16 + l15)*D_ + quad*8;
    load_split8(kp,      khi[s][0], klo[s][0]);
    load_split8(kp + 32, khi[s][1], klo[s][1]);
  }
  if (tid < 64)
    msk[tid] = (mask[(bh>>3)*N_ + kt*64 + tid] == 0) ? 1.f : 0.f;

  float cs[4][4];
  #pragma unroll
  for (int s=0;s<4;++s)
    #pragma unroll
    for (int i=0;i<4;++i) cs[s][i] = 0.f;

  const int iters = NT_/nz;
  for (int rti=0; rti<iters; ++rti){
    const int rt = rz*iters + rti;
    __syncthreads();
    #pragma unroll
    for (int it=0; it<4; ++it){
      int idx = tid + it*256;
      int r = idx>>4, d4 = (idx&15)<<2;
      const float4v v = *(const float4v*)(Qg + (size_t)(rt*64 + r)*D_ + d4);
      unsigned h0,l0,h1,l1;
      split2(v.x, v.y, h0, l0);
      split2(v.z, v.w, h1, l1);
      unsigned* QhiW = (unsigned*)Qhi; unsigned* QloW = (unsigned*)Qlo;
      int base = r*LSW + (d4>>1);
      QhiW[base] = h0; QhiW[base+1] = h1;
      QloW[base] = l0; QloW[base+1] = l1;
    }
    __syncthreads();

    short8 bhi[2], blo[2];
    #pragma unroll
    for (int cc=0; cc<2; ++cc){
      bhi[cc] = *(const short8*)&Qhi[(wv*16+l15)*LS + cc*32 + quad*8];
      blo[cc] = *(const short8*)&Qlo[(wv*16+l15)*LS + cc*32 + quad*8];
    }
    const size_t nrow = (size_t)(bh*NT_ + kt)*N_ + (size_t)rt*64 + wv*16 + l15;
    #pragma unroll
    for (int s=0;s<4;++s){
      float4v c = {0.f,0.f,0.f,0.f};
      #pragma unroll
      for (int cc=0; cc<2; ++cc){
        c = __builtin_amdgcn_mfma_f32_16x16x32_bf16(khi[s][cc], bhi[cc], c, 0,0,0);
        c = __builtin_amdgcn_mfma_f32_16x16x32_bf16(khi[s][cc], blo[cc], c, 0,0,0);
        c = __builtin_amdgcn_mfma_f32_16x16x32_bf16(klo[s][cc], bhi[cc], c, 0,0,0);
      }
      int kl = s*16 + quad*4;
      float sc0 = score_fn(c[0], msk[kl+0]);
      float sc1 = score_fn(c[1], msk[kl+1]);
      float sc2 = score_fn(c[2], msk[kl+2]);
      float sc3 = score_fn(c[3], msk[kl+3]);
      cs[s][0]+=sc0; cs[s][1]+=sc1; cs[s][2]+=sc2; cs[s][3]+=sc3;
      if (STORE){
        uint2 pk;
        pk.x = packbf2(sc0, sc1);
        pk.y = packbf2(sc2, sc3);
        *(uint2*)&S[nrow*64 + kl] = pk;
      }
    }
  }

  #pragma unroll
  for (int s=0;s<4;++s)
    #pragma unroll
    for (int i=0;i<4;++i){
      float v2 = cs[s][i];
      v2 += __shfl_xor(v2, 1);
      v2 += __shfl_xor(v2, 2);
      v2 += __shfl_xor(v2, 4);
      v2 += __shfl_xor(v2, 8);
      cs[s][i] = v2;
    }
  if (l15 == 0){
    #pragma unroll
    for (int s=0;s<4;++s)
      #pragma unroll
      for (int i=0;i<4;++i)
        red[(s*16 + quad*4 + i)*4 + wv] = cs[s][i];
  }
  __syncthreads();
  if (tid < 64){
    float t = red[tid*4+0] + red[tid*4+1] + red[tid*4+2] + red[tid*4+3];
    if (STORE) atomicAdd(&ncw[bh*N_ + kt*64 + tid], t);
    else       ncw[bh*N_ + kt*64 + tid] = 1.0f / sqrtf(t);
  }
}

__global__ __launch_bounds__(256) void k2_w(const float* __restrict__ nc,
                                            float* __restrict__ w){
  int i = blockIdx.x*256 + threadIdx.x;
  w[i] = 1.0f / sqrtf(fmaxf(nc[i], 1e-30f));
}

// k3: out = (S diag(w) V) / (S w); P from global S, rowsum via w-row MFMA.
__global__ __launch_bounds__(256) void k3_pv(
    const float* __restrict__ V, const unsigned short* __restrict__ S,
    const float* __restrict__ w, float* __restrict__ out)
{
  __shared__ unsigned short Vt[80*LS];   // 0..63: (w*V)^T[d][m]; 64: w; 65..79: 0

  const int rt = blockIdx.x, bh = blockIdx.y;
  const int tid = threadIdx.x;
  const int wv = tid>>6, lane = tid&63, quad = lane>>4, l15 = lane&15;

  const float* Vg = V + (size_t)bh*N_*D_;
  const float* wg = w + (size_t)bh*N_;

  {
    unsigned* VtW = (unsigned*)&Vt[64*LS];
    for (int z = tid; z < 16*LSW; z += 256) VtW[z] = 0u;
  }

  float4v acc[4];
  #pragma unroll
  for (int i=0;i<4;++i) acc[i] = (float4v){0.f,0.f,0.f,0.f};
  float4v c5 = {0.f,0.f,0.f,0.f};

  for (int kt=0; kt<NT_; ++kt){
    __syncthreads();
    #pragma unroll
    for (int it=0; it<2; ++it){
      int u = tid + it*256;
      int kp = u & 31;
      int d4 = (u>>5)<<2;
      int m0 = kt*64 + kp*2;
      float wa = wg[m0], wb = wg[m0+1];
      const float* vp = Vg + (size_t)m0*D_ + d4;
      float4v a0 = *(const float4v*)vp;
      float4v a1 = *(const float4v*)(vp + D_);
      unsigned* VtW = (unsigned*)Vt;
      VtW[(d4+0)*LSW + kp] = packbf2(a0.x*wa, a1.x*wb);
      VtW[(d4+1)*LSW + kp] = packbf2(a0.y*wa, a1.y*wb);
      VtW[(d4+2)*LSW + kp] = packbf2(a0.z*wa, a1.z*wb);
      VtW[(d4+3)*LSW + kp] = packbf2(a0.w*wa, a1.w*wb);
    }
    if (tid < 32){
      int m0 = kt*64 + tid*2;
      ((unsigned*)Vt)[64*LSW + tid] = packbf2(wg[m0], wg[m0+1]);
    }
    __syncthreads();

    const size_t base = ((size_t)(bh*NT_ + kt)*N_ + (size_t)rt*64 + wv*16 + l15)*64;
    short8 pf0 = *(const short8*)&S[base +  0 + quad*8];
    short8 pf1 = *(const short8*)&S[base + 32 + quad*8];

    #pragma unroll
    for (int s2=0;s2<4;++s2){
      const short8 a0 = *(const short8*)&Vt[(s2*16+l15)*LS +  0 + quad*8];
      const short8 a1 = *(const short8*)&Vt[(s2*16+l15)*LS + 32 + quad*8];
      acc[s2] = __builtin_amdgcn_mfma_f32_16x16x32_bf16(a0, pf0, acc[s2], 0,0,0);
      acc[s2] = __builtin_amdgcn_mfma_f32_16x16x32_bf16(a1, pf1, acc[s2], 0,0,0);
    }
    {
      const short8 a0 = *(const short8*)&Vt[(64+l15)*LS +  0 + quad*8];
      const short8 a1 = *(const short8*)&Vt[(64+l15)*LS + 32 + quad*8];
      c5 = __builtin_amdgcn_mfma_f32_16x16x32_bf16(a0, pf0, c5, 0,0,0);
      c5 = __builtin_amdgcn_mfma_f32_16x16x32_bf16(a1, pf1, c5, 0,0,0);
    }
  }

  float rs_n = __shfl(c5[0], l15);    // D row 0 (quad0,reg0) col=query row
  float inv = 1.0f / fmaxf(rs_n, 1e-12f);

  float* Og = out + (size_t)bh*N_*D_ + (size_t)(rt*64 + wv*16 + l15)*D_;
  #pragma unroll
  for (int s2=0;s2<4;++s2)
    #pragma unroll
    for (int i=0;i<4;++i)
      Og[s2*16 + quad*4 + i] = acc[s2][i] * inv;
}

// fallback pass2 (round-3, verified): recompute scores, scale by w, PV in-block
__global__ __launch_bounds__(256) void spop_pass2(
    const float* __restrict__ Q, const float* __restrict__ K,
    const float* __restrict__ V, const int* __restrict__ mask,
    const float* __restrict__ w, float* __restrict__ out)
{
  __shared__ unsigned short Khi[64*LS], Klo[64*LS];
  __shared__ unsigned short Vt[64*LS];
  __shared__ unsigned short Ps[64*LS];
  __shared__ float msk[64], wms[64];

  const int rt = blockIdx.x, bh = blockIdx.y, b = bh>>3;
  const int tid = threadIdx.x;
  const int wv = tid>>6, lane = tid&63, quad = lane>>4, l15 = lane&15;

  const float* Qg = Q + (size_t)bh*N_*D_;
  const float* Kg = K + (size_t)bh*N_*D_;
  const float* Vg = V + (size_t)bh*N_*D_;

  short8 qhi[2], qlo[2];
  {
    const float* qp = Qg + (size_t)(rt*64 + wv*16 + l15)*D_ + quad*8;
    load_split8(qp,      qhi[0], qlo[0]);
    load_split8(qp + 32, qhi[1], qlo[1]);
  }

  float4v acc[4];
  #pragma unroll
  for (int i=0;i<4;++i) acc[i] = (float4v){0.f,0.f,0.f,0.f};
  float rs = 0.f;

  for (int kt=0; kt<NT_; ++kt){
    __syncthreads();
    #pragma unroll
    for (int it=0; it<4; ++it){
      int idx = tid + it*256;
      int r = idx>>4, d4 = (idx&15)<<2;
      const float4v v = *(const float4v*)(Kg + (size_t)(kt*64 + r)*D_ + d4);
      unsigned h0,l0,h1,l1;
      split2(v.x, v.y, h0, l0);
      split2(v.z, v.w, h1, l1);
      unsigned* KhiW = (unsigned*)Khi; unsigned* KloW = (unsigned*)Klo;
      int base = r*LSW + (d4>>1);
      KhiW[base] = h0; KhiW[base+1] = h1;
      KloW[base] = l0; KloW[base+1] = l1;
    }
    #pragma unroll
    for (int it=0; it<2; ++it){
      int u = tid + it*256;
      int kp = u & 31;
      int d4 = (u>>5)<<2;
      const float* vp = Vg + (size_t)(kt*64 + kp*2)*D_ + d4;
      float4v a0 = *(const float4v*)vp;
      float4v a1 = *(const float4v*)(vp + D_);
      unsigned* VtW = (unsigned*)Vt;
      VtW[(d4+0)*LSW + kp] = packbf2(a0.x, a1.x);
      VtW[(d4+1)*LSW + kp] = packbf2(a0.y, a1.y);
      VtW[(d4+2)*LSW + kp] = packbf2(a0.z, a1.z);
      VtW[(d4+3)*LSW + kp] = packbf2(a0.w, a1.w);
    }
    if (tid < 64){
      int gk = kt*64 + tid;
      msk[tid] = (mask[b*N_ + gk] == 0) ? 1.f : 0.f;
      wms[tid] = w[bh*N_ + gk];
    }
    __syncthreads();

    #pragma unroll
    for (int s=0;s<4;++s){
      float4v c = {0.f,0.f,0.f,0.f};
      #pragma unroll
      for (int cc=0; cc<2; ++cc){
        const short8 ahi = *(const short8*)&Khi[(s*16+l15)*LS + cc*32 + quad*8];
        const short8 alo = *(const short8*)&Klo[(s*16+l15)*LS + cc*32 + quad*8];
        c = __builtin_amdgcn_mfma_f32_16x16x32_bf16(ahi, qhi[cc], c, 0,0,0);
        c = __builtin_amdgcn_mfma_f32_16x16x32_bf16(ahi, qlo[cc], c, 0,0,0);
        c = __builtin_amdgcn_mfma_f32_16x16x32_bf16(alo, qhi[cc], c, 0,0,0);
      }
      int kl = s*16 + quad*4;
      float sc0 = score_fn(c[0], msk[kl+0]) * wms[kl+0];
      float sc1 = score_fn(c[1], msk[kl+1]) * wms[kl+1];
      float sc2 = score_fn(c[2], msk[kl+2]) * wms[kl+2];
      float sc3 = score_fn(c[3], msk[kl+3]) * wms[kl+3];
      rs += (sc0 + sc1) + (sc2 + sc3);
      unsigned* PsW = (unsigned*)Ps;
      int pb = (wv*16 + l15)*LSW + (kl>>1);
      PsW[pb]   = packbf2(sc0, sc1);
      PsW[pb+1] = packbf2(sc2, sc3);
    }

    short8 pf[2];
    pf[0] = *(const short8*)&Ps[(wv*16+l15)*LS +  0 + quad*8];
    pf[1] = *(const short8*)&Ps[(wv*16+l15)*LS + 32 + quad*8];
    #pragma unroll
    for (int s2=0;s2<4;++s2){
      #pragma unroll
      for (int cc=0; cc<2; ++cc){
        const short8 av = *(const short8*)&Vt[(s2*16+l15)*LS + cc*32 + quad*8];
        acc[s2] = __builtin_amdgcn_mfma_f32_16x16x32_bf16(av, pf[cc], acc[s2], 0,0,0);
      }
    }
  }

  rs += __shfl_xor(rs, 16);
  rs += __shfl_xor(rs, 32);
  float inv = 1.0f / fmaxf(rs, 1e-12f);

  float* Og = out + (size_t)bh*N_*D_ + (size_t)(rt*64 + wv*16 + l15)*D_;
  #pragma unroll
  for (int s2=0;s2<4;++s2)
    #pragma unroll
    for (int i=0;i<4;++i)
      Og[s2*16 + quad*4 + i] = acc[s2][i] * inv;
}

extern "C" void kernel_launch(void* const* d_in, const int* in_sizes, int n_in,
                              void* d_out, int out_size, void* d_ws, size_t ws_size,
                              hipStream_t stream) {
  (void)in_sizes; (void)n_in; (void)out_size;
  const float* Q   = (const float*)d_in[0];
  const float* K   = (const float*)d_in[1];
  const float* V   = (const float*)d_in[2];
  const int*  mask = (const int*)d_in[3];
  float* out = (float*)d_out;

  const size_t need = 262144ull + (size_t)2*BH_*N_*N_;   // nc + w + S(bf16)
  if (ws_size >= need){
    float* nc = (float*)d_ws;
    float* w  = (float*)((char*)d_ws + 131072);
    unsigned short* S = (unsigned short*)((char*)d_ws + 262144);
    hipMemsetAsync(nc, 0, (size_t)BH_*N_*sizeof(float), stream);
    k1_score<true><<<dim3(NT_, BH_, 4), 256, 0, stream>>>(Q, K, mask, nc, S);
    k2_w<<<dim3(BH_*N_/256), 256, 0, stream>>>(nc, w);
    k3_pv<<<dim3(NT_, BH_), 256, 0, stream>>>(V, S, w, out);
  } else {
    float* w = (float*)d_ws;
    k1_score<false><<<dim3(NT_, BH_, 1), 256, 0, stream>>>(Q, K, mask, w, nullptr);
    spop_pass2<<<dim3(NT_, BH_), 256, 0, stream>>>(Q, K, V, mask, w, out);
  }
}